// Round 14
// baseline (249.913 us; speedup 1.0000x reference)
//
#include <hip/hip_runtime.h>

// AUGRU, round 14: 16-wave role-split recurrence (halve per-wave serial stream).
//  Pass 1 (xproj): VERBATIM R12 (~59 us).
//  Pass 2 (rec): 64 blocks x 1024 thr (16 waves), B=16.
//    waves 0-7 (z): phase1 z-rows wh*16 (4 MFMA chain) -> zp in regs;
//                   phase2 same rows: h~ (4 MFMA) + update, h -> LDS (bf16+f32).
//    waves 8-15 (r): phase1 r-rows wh*16 -> rh = sigma(r)*h_f32 -> LDS; idle ph2.
//    2 raw barriers/step. R13 showed step is chain-bound, not issue-bound:
//    halving the per-wave stream is the lever.
// Fallback: proven single-kernel (R2) if ws too small.

#define T_N   200
#define I_DIM 128
#define H_DIM 128
#define NBLK  64
#define TCHUNK 25

typedef float  f32x4  __attribute__((ext_vector_type(4)));
typedef __bf16 bf16x4 __attribute__((ext_vector_type(4)));
typedef __bf16 bf16x8 __attribute__((ext_vector_type(8)));

// preact layout: ((t*NBLK+bblk)*3 + g)*4096 + hidgrp*128 + b*8
#define GATE_BYTES 4096
#define PB_BYTES   (3 * GATE_BYTES)
#define PRE_BYTES  ((size_t)T_N * NBLK * PB_BYTES)   // 157,286,400

// fallback LDS
#define LDA_STRIDE 264
#define LATT_STRIDE 201

__device__ __forceinline__ float fast_sigmoid(float x) {
  float e = __builtin_amdgcn_exp2f(-1.4426950408889634f * x);
  return __builtin_amdgcn_rcpf(1.0f + e);
}
__device__ __forceinline__ float fast_tanh(float x) {
  float e = __builtin_amdgcn_exp2f(2.8853900817779268f * x);
  return 1.0f - 2.0f * __builtin_amdgcn_rcpf(1.0f + e);
}
__device__ __forceinline__ void barrier_lds() {
  asm volatile("s_waitcnt lgkmcnt(0)\n\ts_barrier" ::: "memory");
}
__device__ __forceinline__ bf16x8 pack8(float4 a, float4 b) {
  bf16x8 t;
  t[0] = (__bf16)a.x; t[1] = (__bf16)a.y; t[2] = (__bf16)a.z; t[3] = (__bf16)a.w;
  t[4] = (__bf16)b.x; t[5] = (__bf16)b.y; t[6] = (__bf16)b.z; t[7] = (__bf16)b.w;
  return t;
}
// XOR-swizzled byte offset within a [16 row][256 B] bf16 LDS tile
__device__ __forceinline__ int swz(int row, int bytecol) {
  return row * 256 + (bytecol ^ ((row & 7) << 4));
}
// XOR-swizzled byte offset within a [16 row][512 B] f32 LDS tile
__device__ __forceinline__ int swz32(int row, int bytecol) {
  return row * 512 + (bytecol ^ ((row & 7) << 4));
}

// ---------------------------------------------------------------------------
// Pass 1: x-projections, coop-LDS-staged (VERBATIM R12). 512 blocks, 256 thr.
// ---------------------------------------------------------------------------
__global__ __launch_bounds__(256, 2)
void xproj_kernel(const float* __restrict__ inputs,
                  const float* __restrict__ Wz, const float* __restrict__ bz,
                  const float* __restrict__ Wr, const float* __restrict__ br,
                  const float* __restrict__ Wh, const float* __restrict__ bh,
                  char* __restrict__ pre) {
  __shared__ __align__(16) char lds_x[2 * 4096];

  const int tid  = threadIdx.x;
  const int w    = tid >> 6;
  const int l    = tid & 63;
  const int l15  = l & 15;
  const int lk   = l >> 4;
  const int bblk = blockIdx.x & (NBLK - 1);
  const int t0   = (blockIdx.x >> 6) * TCHUNK;
  const int r0   = bblk * 16;

  const int crow  = tid >> 4;
  const int cslot = tid & 15;
  const float* xsrc = inputs + (size_t)(r0 + crow) * (T_N * I_DIM) + cslot * 8;
  const int cwoff = swz(crow, cslot * 16);

  bf16x8 wb[24];
  f32x4  bias4[6];
  #pragma unroll
  for (int s = 0; s < 6; ++s) {
    int hid0 = w * 32 + (s & 1) * 16;
    const float* Wp; const float* bp;
    if (s < 2)      { Wp = Wz; bp = bz; }
    else if (s < 4) { Wp = Wr; bp = br; }
    else            { Wp = Wh; bp = bh; }
    float4 bv = *(const float4*)&bp[hid0 + lk * 4];
    bias4[s][0] = bv.x; bias4[s][1] = bv.y; bias4[s][2] = bv.z; bias4[s][3] = bv.w;
    const float* Wrow = Wp + (size_t)(hid0 + l15) * 256;
    #pragma unroll
    for (int kt = 0; kt < 4; ++kt) {
      const float* p = Wrow + kt * 32 + lk * 8;
      wb[s * 4 + kt] = pack8(*(const float4*)p, *(const float4*)(p + 4));
    }
  }

  {
    const float* p = xsrc + (size_t)t0 * I_DIM;
    float4 a = *(const float4*)p;
    float4 b = *(const float4*)(p + 4);
    *(bf16x8*)(lds_x + cwoff) = pack8(a, b);
  }
  barrier_lds();

  #pragma unroll 2
  for (int ti = 0; ti < TCHUNK; ++ti) {
    const int t = t0 + ti;
    float4 ra, rb2;
    if (ti + 1 < TCHUNK) {
      const float* p = xsrc + (size_t)(t + 1) * I_DIM;
      ra  = *(const float4*)p;
      rb2 = *(const float4*)(p + 4);
    }

    char* bufc = lds_x + ((ti & 1) ? 4096 : 0);
    bf16x8 xf[4];
    #pragma unroll
    for (int kt = 0; kt < 4; ++kt)
      xf[kt] = *(const bf16x8*)(bufc + swz(l15, kt * 64 + lk * 16));

    f32x4 acc[6];
    #pragma unroll
    for (int s = 0; s < 6; ++s) acc[s] = bias4[s];
    #pragma unroll
    for (int kt = 0; kt < 4; ++kt)
      #pragma unroll
      for (int s = 0; s < 6; ++s)
        acc[s] = __builtin_amdgcn_mfma_f32_16x16x32_bf16(wb[s * 4 + kt], xf[kt], acc[s], 0, 0, 0);

    char* base = pre + ((size_t)t * NBLK + bblk) * PB_BYTES;
    #pragma unroll
    for (int s = 0; s < 6; ++s) {
      int g      = s >> 1;
      int hidgrp = w * 8 + (s & 1) * 4 + lk;
      bf16x4 v;
      v[0] = (__bf16)acc[s][0]; v[1] = (__bf16)acc[s][1];
      v[2] = (__bf16)acc[s][2]; v[3] = (__bf16)acc[s][3];
      *(bf16x4*)(base + g * GATE_BYTES + hidgrp * 128 + l15 * 8) = v;
    }

    if (ti + 1 < TCHUNK) {
      char* bufn = lds_x + (((ti + 1) & 1) ? 4096 : 0);
      *(bf16x8*)(bufn + cwoff) = pack8(ra, rb2);
    }
    barrier_lds();
  }
}

// ---------------------------------------------------------------------------
// Pass 2: recurrence, 64 blocks x 1024 threads (16 waves), role-split.
// ---------------------------------------------------------------------------
__global__ __launch_bounds__(1024, 1)
void augru_rec_kernel(const char* __restrict__ pre,
                      const float* __restrict__ attn,
                      const float* __restrict__ Wz,
                      const float* __restrict__ Wr,
                      const float* __restrict__ Wh,
                      float* __restrict__ out) {
  __shared__ __align__(16) short lds_h [16 * 128];  // bf16 hT, swizzled
  __shared__ __align__(16) short lds_rh[16 * 128];  // bf16 rhT, swizzled
  __shared__ __align__(16) float lds_hf[16 * 128];  // f32 hT, swz32
  __shared__ float lds_att[T_N * 16];               // [t][batch]

  const int tid  = threadIdx.x;
  const int w    = tid >> 6;        // 0..15
  const int l    = tid & 63;
  const int l15  = l & 15;          // batch lane
  const int lk   = l >> 4;
  const int wh   = w & 7;           // hid tile within gate space
  const bool isz = (w < 8);
  const int r0   = blockIdx.x * 16;
  const int myhid = wh * 16 + lk * 4;

  // ---- prologue ----
  for (int idx = tid; idx < T_N * 16; idx += 1024) {
    int t = idx >> 4, b = idx & 15;
    lds_att[idx] = attn[(size_t)(r0 + b) * T_N + t];
  }
  for (int idx = tid; idx < 16 * 128; idx += 1024) {
    lds_h[idx] = 0;
    lds_hf[idx] = 0.0f;
  }

  // ---- A-frags (k=128..255): phase1 gate weights; z-waves also Wh ----
  const float* W1 = isz ? Wz : Wr;
  bf16x8 w1H[4], whH[4];
  {
    const float* p1 = W1 + (size_t)(wh * 16 + l15) * 256 + 128;
    #pragma unroll
    for (int kt = 0; kt < 4; ++kt) {
      const float* a = p1 + kt * 32 + lk * 8;
      w1H[kt] = pack8(*(const float4*)a, *(const float4*)(a + 4));
    }
  }
  if (isz) {
    const float* p2 = Wh + (size_t)(wh * 16 + l15) * 256 + 128;
    #pragma unroll
    for (int kt = 0; kt < 4; ++kt) {
      const float* a = p2 + kt * 32 + lk * 8;
      whH[kt] = pack8(*(const float4*)a, *(const float4*)(a + 4));
    }
  }

  float hreg[4];
  #pragma unroll
  for (int q = 0; q < 4; ++q) hreg[q] = 0.0f;

  // ---- preact ring (depth 2) ----
  // phase1 gate slot: g = isz?0:1 ; z-waves also slot g=2 (h~ preact)
  const char* pbase = pre + (size_t)blockIdx.x * PB_BYTES + (wh * 4 + lk) * 128 + l15 * 8;
  const char* pb1 = pbase + (isz ? 0 : GATE_BYTES);
  const char* pb2 = pbase + 2 * GATE_BYTES;
  const size_t tstride = (size_t)NBLK * PB_BYTES;
  bf16x4 pf1[2], pf2[2];
  #pragma unroll
  for (int d = 0; d < 2; ++d) {
    pf1[d] = *(const bf16x4*)(pb1 + d * tstride);
    if (isz) pf2[d] = *(const bf16x4*)(pb2 + d * tstride);
  }

  const int wr_off  = swz(l15, wh * 32 + lk * 8);     // bf16 b64 write (h or rh)
  const int hf_off  = swz32(l15, wh * 64 + lk * 16);  // f32 b128 (h mirror)

  __syncthreads();

  #pragma unroll 2
  for (int t = 0; t < T_N; ++t) {
    // consume preact t
    float p1v[4], p2v[4];
    #pragma unroll
    for (int q = 0; q < 4; ++q) p1v[q] = (float)pf1[t & 1][q];
    if (isz) {
      #pragma unroll
      for (int q = 0; q < 4; ++q) p2v[q] = (float)pf2[t & 1][q];
    }
    // prefetch t+2
    if (t + 2 < T_N) {
      pf1[t & 1] = *(const bf16x4*)(pb1 + (size_t)(t + 2) * tstride);
      if (isz) pf2[t & 1] = *(const bf16x4*)(pb2 + (size_t)(t + 2) * tstride);
    }

    // h^T B-frags
    bf16x8 hb[4];
    #pragma unroll
    for (int kt = 0; kt < 4; ++kt)
      hb[kt] = *(const bf16x8*)((const char*)lds_h + swz(l15, kt * 64 + lk * 16));

    float av = 0.0f;
    f32x4 hfv;
    if (isz) av = lds_att[t * 16 + l15];
    else     hfv = *(const f32x4*)((const char*)lds_hf + hf_off);

    // phase1: 4-chained MFMA, C = preact
    f32x4 a1;
    a1[0] = p1v[0]; a1[1] = p1v[1]; a1[2] = p1v[2]; a1[3] = p1v[3];
    a1 = __builtin_amdgcn_mfma_f32_16x16x32_bf16(w1H[0], hb[0], a1, 0, 0, 0);
    a1 = __builtin_amdgcn_mfma_f32_16x16x32_bf16(w1H[1], hb[1], a1, 0, 0, 0);
    a1 = __builtin_amdgcn_mfma_f32_16x16x32_bf16(w1H[2], hb[2], a1, 0, 0, 0);
    a1 = __builtin_amdgcn_mfma_f32_16x16x32_bf16(w1H[3], hb[3], a1, 0, 0, 0);

    float zp[4];
    if (isz) {
      #pragma unroll
      for (int q = 0; q < 4; ++q) zp[q] = av * fast_sigmoid(a1[q]);
    } else {
      bf16x4 rhv;
      #pragma unroll
      for (int q = 0; q < 4; ++q) {
        float rr = fast_sigmoid(a1[q]);
        rhv[q] = (__bf16)(rr * hfv[q]);
      }
      *(bf16x4*)((char*)lds_rh + wr_off) = rhv;
    }
    barrier_lds();  // B1: rh visible

    // phase2 (z-waves only)
    if (isz) {
      bf16x8 rb[4];
      #pragma unroll
      for (int kt = 0; kt < 4; ++kt)
        rb[kt] = *(const bf16x8*)((const char*)lds_rh + swz(l15, kt * 64 + lk * 16));
      f32x4 a2;
      a2[0] = p2v[0]; a2[1] = p2v[1]; a2[2] = p2v[2]; a2[3] = p2v[3];
      a2 = __builtin_amdgcn_mfma_f32_16x16x32_bf16(whH[0], rb[0], a2, 0, 0, 0);
      a2 = __builtin_amdgcn_mfma_f32_16x16x32_bf16(whH[1], rb[1], a2, 0, 0, 0);
      a2 = __builtin_amdgcn_mfma_f32_16x16x32_bf16(whH[2], rb[2], a2, 0, 0, 0);
      a2 = __builtin_amdgcn_mfma_f32_16x16x32_bf16(whH[3], rb[3], a2, 0, 0, 0);

      bf16x4 hbv;
      f32x4  hfw;
      #pragma unroll
      for (int q = 0; q < 4; ++q) {
        float ht = fast_tanh(a2[q]);
        float hn = __builtin_fmaf(zp[q], ht - hreg[q], hreg[q]);
        hreg[q] = hn;
        hbv[q] = (__bf16)hn;
        hfw[q] = hn;
      }
      *(bf16x4*)((char*)lds_h + wr_off) = hbv;
      *(f32x4*)((char*)lds_hf + hf_off) = hfw;
    }
    barrier_lds();  // B2: h visible
  }

  if (isz) {
    float4 o;
    o.x = hreg[0]; o.y = hreg[1]; o.z = hreg[2]; o.w = hreg[3];
    *(float4*)&out[(size_t)(r0 + l15) * H_DIM + myhid] = o;
  }
}

// ---------------------------------------------------------------------------
// Fallback: proven single-kernel version (round 2, 410 us).
// ---------------------------------------------------------------------------
__global__ __launch_bounds__(256, 1)
void augru_kernel(const float* __restrict__ inputs,
                  const float* __restrict__ attn,
                  const float* __restrict__ Wz, const float* __restrict__ bz,
                  const float* __restrict__ Wr, const float* __restrict__ br,
                  const float* __restrict__ Wh, const float* __restrict__ bh,
                  float* __restrict__ out) {
  __shared__ __align__(16) short lds_a[16 * LDA_STRIDE];
  __shared__ float lds_att[16 * LATT_STRIDE];

  const int tid = threadIdx.x;
  const int w   = tid >> 6;
  const int l   = tid & 63;
  const int l15 = l & 15;
  const int lk  = l >> 4;
  const int r0  = blockIdx.x * 16;

  for (int idx = tid; idx < 16 * T_N; idx += 256) {
    int row = idx / T_N, t = idx - row * T_N;
    lds_att[row * LATT_STRIDE + t] = attn[(size_t)(r0 + row) * T_N + t];
  }
  for (int idx = tid; idx < 16 * H_DIM; idx += 256) {
    int row = idx >> 7, c = idx & 127;
    lds_a[row * LDA_STRIDE + c] = 0;
  }

  bf16x8 w1[32];
  float  bias1[4];
  #pragma unroll
  for (int ct = 0; ct < 4; ++ct) {
    int n = w * 32 + (ct & 1) * 16 + l15;
    const float* Wp; float bv;
    if (ct < 2) { Wp = Wz + (size_t)n * 256; bv = bz[n]; }
    else        { Wp = Wr + (size_t)n * 256; bv = br[n]; }
    bias1[ct] = bv;
    #pragma unroll
    for (int kt = 0; kt < 8; ++kt) {
      const float* p = Wp + kt * 32 + lk * 8;
      w1[ct * 8 + kt] = pack8(*(const float4*)p, *(const float4*)(p + 4));
    }
  }
  bf16x8 w2[16];
  float  bias2[2];
  #pragma unroll
  for (int ct = 0; ct < 2; ++ct) {
    int n = w * 32 + ct * 16 + l15;
    bias2[ct] = bh[n];
    const float* Wp = Wh + (size_t)n * 256;
    #pragma unroll
    for (int kt = 0; kt < 8; ++kt) {
      const float* p = Wp + kt * 32 + lk * 8;
      w2[ct * 8 + kt] = pack8(*(const float4*)p, *(const float4*)(p + 4));
    }
  }

  float hreg[2][4];
  #pragma unroll
  for (int ct = 0; ct < 2; ++ct)
    #pragma unroll
    for (int q = 0; q < 4; ++q) hreg[ct][q] = 0.0f;

  const float* xbase = inputs + (size_t)(r0 + l15) * (T_N * I_DIM);
  bf16x8 xfrag[4];
  #pragma unroll
  for (int kt = 0; kt < 4; ++kt) {
    const float* p = xbase + kt * 32 + lk * 8;
    xfrag[kt] = pack8(*(const float4*)p, *(const float4*)(p + 4));
  }

  __syncthreads();

  float4 xr0[4], xr1[4];
  for (int t = 0; t < T_N; ++t) {
    if (t + 1 < T_N) {
      #pragma unroll
      for (int kt = 0; kt < 4; ++kt) {
        const float* p = xbase + (size_t)(t + 1) * I_DIM + kt * 32 + lk * 8;
        xr0[kt] = *(const float4*)p;
        xr1[kt] = *(const float4*)(p + 4);
      }
    }
    bf16x8 hfrag[4];
    #pragma unroll
    for (int kt = 0; kt < 4; ++kt)
      hfrag[kt] = *(const bf16x8*)&lds_a[l15 * LDA_STRIDE + kt * 32 + lk * 8];
    float av[4];
    #pragma unroll
    for (int q = 0; q < 4; ++q) av[q] = lds_att[(lk * 4 + q) * LATT_STRIDE + t];

    f32x4 acc[4];
    #pragma unroll
    for (int ct = 0; ct < 4; ++ct) {
      f32x4 a; a[0] = bias1[ct]; a[1] = bias1[ct]; a[2] = bias1[ct]; a[3] = bias1[ct];
      acc[ct] = a;
    }
    #pragma unroll
    for (int kt = 0; kt < 4; ++kt)
      #pragma unroll
      for (int ct = 0; ct < 4; ++ct)
        acc[ct] = __builtin_amdgcn_mfma_f32_16x16x32_bf16(xfrag[kt], w1[ct * 8 + kt], acc[ct], 0, 0, 0);

    f32x4 acc2[2];
    #pragma unroll
    for (int ct = 0; ct < 2; ++ct) {
      f32x4 a; a[0] = bias2[ct]; a[1] = bias2[ct]; a[2] = bias2[ct]; a[3] = bias2[ct];
      acc2[ct] = a;
    }
    #pragma unroll
    for (int kt = 0; kt < 4; ++kt)
      #pragma unroll
      for (int ct = 0; ct < 2; ++ct)
        acc2[ct] = __builtin_amdgcn_mfma_f32_16x16x32_bf16(xfrag[kt], w2[ct * 8 + kt], acc2[ct], 0, 0, 0);

    #pragma unroll
    for (int kt = 0; kt < 4; ++kt)
      #pragma unroll
      for (int ct = 0; ct < 4; ++ct)
        acc[ct] = __builtin_amdgcn_mfma_f32_16x16x32_bf16(hfrag[kt], w1[ct * 8 + 4 + kt], acc[ct], 0, 0, 0);

    float zp[2][4];
    #pragma unroll
    for (int ct = 0; ct < 2; ++ct) {
      int col = w * 32 + ct * 16 + l15;
      #pragma unroll
      for (int q = 0; q < 4; ++q) {
        int row = lk * 4 + q;
        zp[ct][q] = av[q] * fast_sigmoid(acc[ct][q]);
        float rr = fast_sigmoid(acc[2 + ct][q]);
        __bf16 rhb = (__bf16)(rr * hreg[ct][q]);
        lds_a[row * LDA_STRIDE + 128 + col] = __builtin_bit_cast(short, rhb);
      }
    }
    barrier_lds();

    bf16x8 rfrag[4];
    #pragma unroll
    for (int kt = 0; kt < 4; ++kt)
      rfrag[kt] = *(const bf16x8*)&lds_a[l15 * LDA_STRIDE + 128 + kt * 32 + lk * 8];
    #pragma unroll
    for (int kt = 0; kt < 4; ++kt)
      #pragma unroll
      for (int ct = 0; ct < 2; ++ct)
        acc2[ct] = __builtin_amdgcn_mfma_f32_16x16x32_bf16(rfrag[kt], w2[ct * 8 + 4 + kt], acc2[ct], 0, 0, 0);

    if (t + 1 < T_N) {
      #pragma unroll
      for (int kt = 0; kt < 4; ++kt)
        xfrag[kt] = pack8(xr0[kt], xr1[kt]);
    }

    #pragma unroll
    for (int ct = 0; ct < 2; ++ct) {
      int col = w * 32 + ct * 16 + l15;
      #pragma unroll
      for (int q = 0; q < 4; ++q) {
        int row = lk * 4 + q;
        float ht = fast_tanh(acc2[ct][q]);
        float ho = hreg[ct][q];
        float hn = __builtin_fmaf(zp[ct][q], ht - ho, ho);
        hreg[ct][q] = hn;
        __bf16 hb = (__bf16)hn;
        lds_a[row * LDA_STRIDE + col] = __builtin_bit_cast(short, hb);
      }
    }
    barrier_lds();
  }

  #pragma unroll
  for (int ct = 0; ct < 2; ++ct) {
    int col = w * 32 + ct * 16 + l15;
    #pragma unroll
    for (int q = 0; q < 4; ++q) {
      int row = lk * 4 + q;
      out[(size_t)(r0 + row) * H_DIM + col] = hreg[ct][q];
    }
  }
}

extern "C" void kernel_launch(void* const* d_in, const int* in_sizes, int n_in,
                              void* d_out, int out_size, void* d_ws, size_t ws_size,
                              hipStream_t stream) {
  (void)in_sizes; (void)n_in; (void)out_size;
  const float* inputs = (const float*)d_in[0];
  const float* attn   = (const float*)d_in[1];
  const float* Wz     = (const float*)d_in[2];
  const float* bz     = (const float*)d_in[3];
  const float* Wr     = (const float*)d_in[4];
  const float* br     = (const float*)d_in[5];
  const float* Wh     = (const float*)d_in[6];
  const float* bh     = (const float*)d_in[7];
  float* out = (float*)d_out;

  if (ws_size >= PRE_BYTES) {
    char* pre = (char*)d_ws;
    xproj_kernel<<<NBLK * (T_N / TCHUNK), 256, 0, stream>>>(inputs, Wz, bz, Wr, br, Wh, bh, pre);
    augru_rec_kernel<<<NBLK, 1024, 0, stream>>>(pre, attn, Wz, Wr, Wh, out);
  } else {
    augru_kernel<<<NBLK, 256, 0, stream>>>(inputs, attn, Wz, bz, Wr, br, Wh, bh, out);
  }
}

// Round 15
// 225.504 us; speedup vs baseline: 1.1082x; 1.1082x over previous
//
#include <hip/hip_runtime.h>

// AUGRU, round 15: R12 + fragment-major (conflict-free) LDS layout for h/rh.
//  Pass 1 (xproj): VERBATIM R12 (~59 us).
//  Pass 2 (rec): R12 structure (64 blocks x 8 waves), but lds_h/lds_rh stored
//     in exact B-frag order: byte = kt*1024 + (lk*16+l15)*16. Wave b128 reads
//     = 64 consecutive 16B slots -> conflict-free (was ~8-way, 320 cyc/step).
//     Writes: one b64 per thread at the bijective frag address (~4-way, rare).
//     Preact ring pointer strength-reduced. Zero arithmetic changes.
// Fallback: proven single-kernel (R2) if ws too small.

#define T_N   200
#define I_DIM 128
#define H_DIM 128
#define NBLK  64
#define TCHUNK 25

typedef float  f32x4  __attribute__((ext_vector_type(4)));
typedef __bf16 bf16x4 __attribute__((ext_vector_type(4)));
typedef __bf16 bf16x8 __attribute__((ext_vector_type(8)));

// preact layout: ((t*NBLK+bblk)*3 + g)*4096 + hidgrp*128 + b*8
#define GATE_BYTES 4096
#define PB_BYTES   (3 * GATE_BYTES)
#define PRE_BYTES  ((size_t)T_N * NBLK * PB_BYTES)   // 157,286,400

// fallback LDS
#define LDA_STRIDE 264
#define LATT_STRIDE 201

__device__ __forceinline__ float fast_sigmoid(float x) {
  float e = __builtin_amdgcn_exp2f(-1.4426950408889634f * x);
  return __builtin_amdgcn_rcpf(1.0f + e);
}
__device__ __forceinline__ float fast_tanh(float x) {
  float e = __builtin_amdgcn_exp2f(2.8853900817779268f * x);
  return 1.0f - 2.0f * __builtin_amdgcn_rcpf(1.0f + e);
}
__device__ __forceinline__ void barrier_lds() {
  asm volatile("s_waitcnt lgkmcnt(0)\n\ts_barrier" ::: "memory");
}
__device__ __forceinline__ bf16x8 pack8(float4 a, float4 b) {
  bf16x8 t;
  t[0] = (__bf16)a.x; t[1] = (__bf16)a.y; t[2] = (__bf16)a.z; t[3] = (__bf16)a.w;
  t[4] = (__bf16)b.x; t[5] = (__bf16)b.y; t[6] = (__bf16)b.z; t[7] = (__bf16)b.w;
  return t;
}
// XOR-swizzled byte offset within a [16 row][256 B] bf16 LDS tile (xproj only)
__device__ __forceinline__ int swz(int row, int bytecol) {
  return row * 256 + (bytecol ^ ((row & 7) << 4));
}

// ---------------------------------------------------------------------------
// Pass 1: x-projections, coop-LDS-staged (VERBATIM R12). 512 blocks, 256 thr.
// ---------------------------------------------------------------------------
__global__ __launch_bounds__(256, 2)
void xproj_kernel(const float* __restrict__ inputs,
                  const float* __restrict__ Wz, const float* __restrict__ bz,
                  const float* __restrict__ Wr, const float* __restrict__ br,
                  const float* __restrict__ Wh, const float* __restrict__ bh,
                  char* __restrict__ pre) {
  __shared__ __align__(16) char lds_x[2 * 4096];

  const int tid  = threadIdx.x;
  const int w    = tid >> 6;
  const int l    = tid & 63;
  const int l15  = l & 15;
  const int lk   = l >> 4;
  const int bblk = blockIdx.x & (NBLK - 1);
  const int t0   = (blockIdx.x >> 6) * TCHUNK;
  const int r0   = bblk * 16;

  const int crow  = tid >> 4;
  const int cslot = tid & 15;
  const float* xsrc = inputs + (size_t)(r0 + crow) * (T_N * I_DIM) + cslot * 8;
  const int cwoff = swz(crow, cslot * 16);

  bf16x8 wb[24];
  f32x4  bias4[6];
  #pragma unroll
  for (int s = 0; s < 6; ++s) {
    int hid0 = w * 32 + (s & 1) * 16;
    const float* Wp; const float* bp;
    if (s < 2)      { Wp = Wz; bp = bz; }
    else if (s < 4) { Wp = Wr; bp = br; }
    else            { Wp = Wh; bp = bh; }
    float4 bv = *(const float4*)&bp[hid0 + lk * 4];
    bias4[s][0] = bv.x; bias4[s][1] = bv.y; bias4[s][2] = bv.z; bias4[s][3] = bv.w;
    const float* Wrow = Wp + (size_t)(hid0 + l15) * 256;
    #pragma unroll
    for (int kt = 0; kt < 4; ++kt) {
      const float* p = Wrow + kt * 32 + lk * 8;
      wb[s * 4 + kt] = pack8(*(const float4*)p, *(const float4*)(p + 4));
    }
  }

  {
    const float* p = xsrc + (size_t)t0 * I_DIM;
    float4 a = *(const float4*)p;
    float4 b = *(const float4*)(p + 4);
    *(bf16x8*)(lds_x + cwoff) = pack8(a, b);
  }
  barrier_lds();

  #pragma unroll 2
  for (int ti = 0; ti < TCHUNK; ++ti) {
    const int t = t0 + ti;
    float4 ra, rb2;
    if (ti + 1 < TCHUNK) {
      const float* p = xsrc + (size_t)(t + 1) * I_DIM;
      ra  = *(const float4*)p;
      rb2 = *(const float4*)(p + 4);
    }

    char* bufc = lds_x + ((ti & 1) ? 4096 : 0);
    bf16x8 xf[4];
    #pragma unroll
    for (int kt = 0; kt < 4; ++kt)
      xf[kt] = *(const bf16x8*)(bufc + swz(l15, kt * 64 + lk * 16));

    f32x4 acc[6];
    #pragma unroll
    for (int s = 0; s < 6; ++s) acc[s] = bias4[s];
    #pragma unroll
    for (int kt = 0; kt < 4; ++kt)
      #pragma unroll
      for (int s = 0; s < 6; ++s)
        acc[s] = __builtin_amdgcn_mfma_f32_16x16x32_bf16(wb[s * 4 + kt], xf[kt], acc[s], 0, 0, 0);

    char* base = pre + ((size_t)t * NBLK + bblk) * PB_BYTES;
    #pragma unroll
    for (int s = 0; s < 6; ++s) {
      int g      = s >> 1;
      int hidgrp = w * 8 + (s & 1) * 4 + lk;
      bf16x4 v;
      v[0] = (__bf16)acc[s][0]; v[1] = (__bf16)acc[s][1];
      v[2] = (__bf16)acc[s][2]; v[3] = (__bf16)acc[s][3];
      *(bf16x4*)(base + g * GATE_BYTES + hidgrp * 128 + l15 * 8) = v;
    }

    if (ti + 1 < TCHUNK) {
      char* bufn = lds_x + (((ti + 1) & 1) ? 4096 : 0);
      *(bf16x8*)(bufn + cwoff) = pack8(ra, rb2);
    }
    barrier_lds();
  }
}

// ---------------------------------------------------------------------------
// Pass 2: recurrence, 64 blocks x 8 waves, fragment-major LDS.
// ---------------------------------------------------------------------------
__global__ __launch_bounds__(512, 1)
void augru_rec_kernel(const char* __restrict__ pre,
                      const float* __restrict__ attn,
                      const float* __restrict__ Wz,
                      const float* __restrict__ Wr,
                      const float* __restrict__ Wh,
                      float* __restrict__ out) {
  __shared__ __align__(16) char lds_h [4096];   // frag-major bf16 h
  __shared__ __align__(16) char lds_rh[4096];   // frag-major bf16 rh
  __shared__ float lds_att[T_N * 16];           // [t][batch]

  const int tid   = threadIdx.x;
  const int w     = tid >> 6;
  const int l     = tid & 63;
  const int l15   = l & 15;          // batch lane
  const int lk    = l >> 4;
  const int r0    = blockIdx.x * 16;
  const int myhid = w * 16 + lk * 4;

  for (int idx = tid; idx < T_N * 16; idx += 512) {
    int t = idx >> 4, b = idx & 15;
    lds_att[idx] = attn[(size_t)(r0 + b) * T_N + t];
  }
  for (int idx = tid; idx < 1024; idx += 512)
    ((float4*)lds_h)[idx >> 2][idx & 3] = 0.0f;  // zero 4096B via f32 lanes
  // simpler: zero bytes
  for (int idx = tid * 4; idx < 4096; idx += 512 * 4)
    *(float*)(lds_h + idx) = 0.0f;

  bf16x8 wzH[4], wrH[4], whH[4];
  {
    const float* pz = Wz + (size_t)(w * 16 + l15) * 256 + 128;
    const float* pr = Wr + (size_t)(w * 16 + l15) * 256 + 128;
    const float* ph = Wh + (size_t)(w * 16 + l15) * 256 + 128;
    #pragma unroll
    for (int kt = 0; kt < 4; ++kt) {
      const float* a = pz + kt * 32 + lk * 8;
      wzH[kt] = pack8(*(const float4*)a, *(const float4*)(a + 4));
      const float* b = pr + kt * 32 + lk * 8;
      wrH[kt] = pack8(*(const float4*)b, *(const float4*)(b + 4));
      const float* cc = ph + kt * 32 + lk * 8;
      whH[kt] = pack8(*(const float4*)cc, *(const float4*)(cc + 4));
    }
  }

  float hreg[4];
  #pragma unroll
  for (int q = 0; q < 4; ++q) hreg[q] = 0.0f;

  // preact ring (depth 2), strength-reduced pointer walk
  const char* pb = pre + (size_t)blockIdx.x * PB_BYTES + (w * 4 + lk) * 128 + l15 * 8;
  const size_t tstride = (size_t)NBLK * PB_BYTES;
  bf16x4 pf[2][3];
  #pragma unroll
  for (int d = 0; d < 2; ++d)
    #pragma unroll
    for (int g = 0; g < 3; ++g)
      pf[d][g] = *(const bf16x4*)(pb + d * tstride + g * GATE_BYTES);
  const char* pnx = pb + 2 * tstride;   // prefetch pointer for t+2

  // frag-major offsets:
  // read  (per kt): kt*1024 + (lk*16 + l15)*16
  // write (one b64): (w>>1)*1024 + (((w&1)*2 + (lk>>1))*16 + l15)*16 + (lk&1)*8
  const int rd_base = (lk * 16 + l15) * 16;
  const int wr_off  = (w >> 1) * 1024 + ((((w & 1) * 2) + (lk >> 1)) * 16 + l15) * 16 + (lk & 1) * 8;

  __syncthreads();

  #pragma unroll 2
  for (int t = 0; t < T_N; ++t) {
    float pzv[4], prv[4], phv[4];
    #pragma unroll
    for (int q = 0; q < 4; ++q) {
      pzv[q] = (float)pf[t & 1][0][q];
      prv[q] = (float)pf[t & 1][1][q];
      phv[q] = (float)pf[t & 1][2][q];
    }
    if (t + 2 < T_N) {
      #pragma unroll
      for (int g = 0; g < 3; ++g)
        pf[t & 1][g] = *(const bf16x4*)(pnx + g * GATE_BYTES);
      pnx += tstride;
    }

    bf16x8 hb[4];
    #pragma unroll
    for (int kt = 0; kt < 4; ++kt)
      hb[kt] = *(const bf16x8*)(lds_h + kt * 1024 + rd_base);
    const float av = lds_att[t * 16 + l15];

    f32x4 zA, zB, rA, rB;
    { f32x4 a; a[0]=pzv[0]; a[1]=pzv[1]; a[2]=pzv[2]; a[3]=pzv[3]; zA = a; }
    { f32x4 a; a[0]=prv[0]; a[1]=prv[1]; a[2]=prv[2]; a[3]=prv[3]; rA = a; }
    { f32x4 z; z[0]=0.f; z[1]=0.f; z[2]=0.f; z[3]=0.f; zB = z; rB = z; }
    zA = __builtin_amdgcn_mfma_f32_16x16x32_bf16(wzH[0], hb[0], zA, 0, 0, 0);
    rA = __builtin_amdgcn_mfma_f32_16x16x32_bf16(wrH[0], hb[0], rA, 0, 0, 0);
    zB = __builtin_amdgcn_mfma_f32_16x16x32_bf16(wzH[1], hb[1], zB, 0, 0, 0);
    rB = __builtin_amdgcn_mfma_f32_16x16x32_bf16(wrH[1], hb[1], rB, 0, 0, 0);
    zA = __builtin_amdgcn_mfma_f32_16x16x32_bf16(wzH[2], hb[2], zA, 0, 0, 0);
    rA = __builtin_amdgcn_mfma_f32_16x16x32_bf16(wrH[2], hb[2], rA, 0, 0, 0);
    zB = __builtin_amdgcn_mfma_f32_16x16x32_bf16(wzH[3], hb[3], zB, 0, 0, 0);
    rB = __builtin_amdgcn_mfma_f32_16x16x32_bf16(wrH[3], hb[3], rB, 0, 0, 0);

    bf16x4 rhv;
    #pragma unroll
    for (int q = 0; q < 4; ++q) {
      float rr = fast_sigmoid(rA[q] + rB[q]);
      rhv[q] = (__bf16)(rr * hreg[q]);
    }
    *(bf16x4*)(lds_rh + wr_off) = rhv;
    float zp[4];
    #pragma unroll
    for (int q = 0; q < 4; ++q)
      zp[q] = av * fast_sigmoid(zA[q] + zB[q]);
    barrier_lds();  // B1: rh visible

    bf16x8 rb[4];
    #pragma unroll
    for (int kt = 0; kt < 4; ++kt)
      rb[kt] = *(const bf16x8*)(lds_rh + kt * 1024 + rd_base);
    f32x4 hA, hB;
    { f32x4 a; a[0]=phv[0]; a[1]=phv[1]; a[2]=phv[2]; a[3]=phv[3]; hA = a; }
    { f32x4 z; z[0]=0.f; z[1]=0.f; z[2]=0.f; z[3]=0.f; hB = z; }
    hA = __builtin_amdgcn_mfma_f32_16x16x32_bf16(whH[0], rb[0], hA, 0, 0, 0);
    hB = __builtin_amdgcn_mfma_f32_16x16x32_bf16(whH[1], rb[1], hB, 0, 0, 0);
    hA = __builtin_amdgcn_mfma_f32_16x16x32_bf16(whH[2], rb[2], hA, 0, 0, 0);
    hB = __builtin_amdgcn_mfma_f32_16x16x32_bf16(whH[3], rb[3], hB, 0, 0, 0);

    bf16x4 hbv;
    #pragma unroll
    for (int q = 0; q < 4; ++q) {
      float ht = fast_tanh(hA[q] + hB[q]);
      float hn = __builtin_fmaf(zp[q], ht - hreg[q], hreg[q]);
      hreg[q] = hn;
      hbv[q] = (__bf16)hn;
    }
    *(bf16x4*)(lds_h + wr_off) = hbv;
    barrier_lds();  // B2: h visible
  }

  float4 o;
  o.x = hreg[0]; o.y = hreg[1]; o.z = hreg[2]; o.w = hreg[3];
  *(float4*)&out[(size_t)(r0 + l15) * H_DIM + myhid] = o;
}

// ---------------------------------------------------------------------------
// Fallback: proven single-kernel version (round 2, 410 us).
// ---------------------------------------------------------------------------
__global__ __launch_bounds__(256, 1)
void augru_kernel(const float* __restrict__ inputs,
                  const float* __restrict__ attn,
                  const float* __restrict__ Wz, const float* __restrict__ bz,
                  const float* __restrict__ Wr, const float* __restrict__ br,
                  const float* __restrict__ Wh, const float* __restrict__ bh,
                  float* __restrict__ out) {
  __shared__ __align__(16) short lds_a[16 * LDA_STRIDE];
  __shared__ float lds_att[16 * LATT_STRIDE];

  const int tid = threadIdx.x;
  const int w   = tid >> 6;
  const int l   = tid & 63;
  const int l15 = l & 15;
  const int lk  = l >> 4;
  const int r0  = blockIdx.x * 16;

  for (int idx = tid; idx < 16 * T_N; idx += 256) {
    int row = idx / T_N, t = idx - row * T_N;
    lds_att[row * LATT_STRIDE + t] = attn[(size_t)(r0 + row) * T_N + t];
  }
  for (int idx = tid; idx < 16 * H_DIM; idx += 256) {
    int row = idx >> 7, c = idx & 127;
    lds_a[row * LDA_STRIDE + c] = 0;
  }

  bf16x8 w1[32];
  float  bias1[4];
  #pragma unroll
  for (int ct = 0; ct < 4; ++ct) {
    int n = w * 32 + (ct & 1) * 16 + l15;
    const float* Wp; float bv;
    if (ct < 2) { Wp = Wz + (size_t)n * 256; bv = bz[n]; }
    else        { Wp = Wr + (size_t)n * 256; bv = br[n]; }
    bias1[ct] = bv;
    #pragma unroll
    for (int kt = 0; kt < 8; ++kt) {
      const float* p = Wp + kt * 32 + lk * 8;
      w1[ct * 8 + kt] = pack8(*(const float4*)p, *(const float4*)(p + 4));
    }
  }
  bf16x8 w2[16];
  float  bias2[2];
  #pragma unroll
  for (int ct = 0; ct < 2; ++ct) {
    int n = w * 32 + ct * 16 + l15;
    bias2[ct] = bh[n];
    const float* Wp = Wh + (size_t)n * 256;
    #pragma unroll
    for (int kt = 0; kt < 8; ++kt) {
      const float* p = Wp + kt * 32 + lk * 8;
      w2[ct * 8 + kt] = pack8(*(const float4*)p, *(const float4*)(p + 4));
    }
  }

  float hreg[2][4];
  #pragma unroll
  for (int ct = 0; ct < 2; ++ct)
    #pragma unroll
    for (int q = 0; q < 4; ++q) hreg[ct][q] = 0.0f;

  const float* xbase = inputs + (size_t)(r0 + l15) * (T_N * I_DIM);
  bf16x8 xfrag[4];
  #pragma unroll
  for (int kt = 0; kt < 4; ++kt) {
    const float* p = xbase + kt * 32 + lk * 8;
    xfrag[kt] = pack8(*(const float4*)p, *(const float4*)(p + 4));
  }

  __syncthreads();

  float4 xr0[4], xr1[4];
  for (int t = 0; t < T_N; ++t) {
    if (t + 1 < T_N) {
      #pragma unroll
      for (int kt = 0; kt < 4; ++kt) {
        const float* p = xbase + (size_t)(t + 1) * I_DIM + kt * 32 + lk * 8;
        xr0[kt] = *(const float4*)p;
        xr1[kt] = *(const float4*)(p + 4);
      }
    }
    bf16x8 hfrag[4];
    #pragma unroll
    for (int kt = 0; kt < 4; ++kt)
      hfrag[kt] = *(const bf16x8*)&lds_a[l15 * LDA_STRIDE + kt * 32 + lk * 8];
    float av[4];
    #pragma unroll
    for (int q = 0; q < 4; ++q) av[q] = lds_att[(lk * 4 + q) * LATT_STRIDE + t];

    f32x4 acc[4];
    #pragma unroll
    for (int ct = 0; ct < 4; ++ct) {
      f32x4 a; a[0] = bias1[ct]; a[1] = bias1[ct]; a[2] = bias1[ct]; a[3] = bias1[ct];
      acc[ct] = a;
    }
    #pragma unroll
    for (int kt = 0; kt < 4; ++kt)
      #pragma unroll
      for (int ct = 0; ct < 4; ++ct)
        acc[ct] = __builtin_amdgcn_mfma_f32_16x16x32_bf16(xfrag[kt], w1[ct * 8 + kt], acc[ct], 0, 0, 0);

    f32x4 acc2[2];
    #pragma unroll
    for (int ct = 0; ct < 2; ++ct) {
      f32x4 a; a[0] = bias2[ct]; a[1] = bias2[ct]; a[2] = bias2[ct]; a[3] = bias2[ct];
      acc2[ct] = a;
    }
    #pragma unroll
    for (int kt = 0; kt < 4; ++kt)
      #pragma unroll
      for (int ct = 0; ct < 2; ++ct)
        acc2[ct] = __builtin_amdgcn_mfma_f32_16x16x32_bf16(xfrag[kt], w2[ct * 8 + kt], acc2[ct], 0, 0, 0);

    #pragma unroll
    for (int kt = 0; kt < 4; ++kt)
      #pragma unroll
      for (int ct = 0; ct < 4; ++ct)
        acc[ct] = __builtin_amdgcn_mfma_f32_16x16x32_bf16(hfrag[kt], w1[ct * 8 + 4 + kt], acc[ct], 0, 0, 0);

    float zp[2][4];
    #pragma unroll
    for (int ct = 0; ct < 2; ++ct) {
      int col = w * 32 + ct * 16 + l15;
      #pragma unroll
      for (int q = 0; q < 4; ++q) {
        int row = lk * 4 + q;
        zp[ct][q] = av[q] * fast_sigmoid(acc[ct][q]);
        float rr = fast_sigmoid(acc[2 + ct][q]);
        __bf16 rhb = (__bf16)(rr * hreg[ct][q]);
        lds_a[row * LDA_STRIDE + 128 + col] = __builtin_bit_cast(short, rhb);
      }
    }
    barrier_lds();

    bf16x8 rfrag[4];
    #pragma unroll
    for (int kt = 0; kt < 4; ++kt)
      rfrag[kt] = *(const bf16x8*)&lds_a[l15 * LDA_STRIDE + 128 + kt * 32 + lk * 8];
    #pragma unroll
    for (int kt = 0; kt < 4; ++kt)
      #pragma unroll
      for (int ct = 0; ct < 2; ++ct)
        acc2[ct] = __builtin_amdgcn_mfma_f32_16x16x32_bf16(rfrag[kt], w2[ct * 8 + 4 + kt], acc2[ct], 0, 0, 0);

    if (t + 1 < T_N) {
      #pragma unroll
      for (int kt = 0; kt < 4; ++kt)
        xfrag[kt] = pack8(xr0[kt], xr1[kt]);
    }

    #pragma unroll
    for (int ct = 0; ct < 2; ++ct) {
      int col = w * 32 + ct * 16 + l15;
      #pragma unroll
      for (int q = 0; q < 4; ++q) {
        int row = lk * 4 + q;
        float ht = fast_tanh(acc2[ct][q]);
        float ho = hreg[ct][q];
        float hn = __builtin_fmaf(zp[ct][q], ht - ho, ho);
        hreg[ct][q] = hn;
        __bf16 hb = (__bf16)hn;
        lds_a[row * LDA_STRIDE + col] = __builtin_bit_cast(short, hb);
      }
    }
    barrier_lds();
  }

  #pragma unroll
  for (int ct = 0; ct < 2; ++ct) {
    int col = w * 32 + ct * 16 + l15;
    #pragma unroll
    for (int q = 0; q < 4; ++q) {
      int row = lk * 4 + q;
      out[(size_t)(r0 + row) * H_DIM + col] = hreg[ct][q];
    }
  }
}

extern "C" void kernel_launch(void* const* d_in, const int* in_sizes, int n_in,
                              void* d_out, int out_size, void* d_ws, size_t ws_size,
                              hipStream_t stream) {
  (void)in_sizes; (void)n_in; (void)out_size;
  const float* inputs = (const float*)d_in[0];
  const float* attn   = (const float*)d_in[1];
  const float* Wz     = (const float*)d_in[2];
  const float* bz     = (const float*)d_in[3];
  const float* Wr     = (const float*)d_in[4];
  const float* br     = (const float*)d_in[5];
  const float* Wh     = (const float*)d_in[6];
  const float* bh     = (const float*)d_in[7];
  float* out = (float*)d_out;

  if (ws_size >= PRE_BYTES) {
    char* pre = (char*)d_ws;
    xproj_kernel<<<NBLK * (T_N / TCHUNK), 256, 0, stream>>>(inputs, Wz, bz, Wr, br, Wh, bh, pre);
    augru_rec_kernel<<<NBLK, 512, 0, stream>>>(pre, attn, Wz, Wr, Wh, out);
  } else {
    augru_kernel<<<NBLK, 256, 0, stream>>>(inputs, attn, Wz, bz, Wr, br, Wh, bh, out);
  }
}